// Round 4
// baseline (429.637 us; speedup 1.0000x reference)
//
#include <hip/hip_runtime.h>
#include <cstdint>

#define M_DIM 4096
#define K_DIM 16384
#define N_DIM 256
#define SPLIT 8
#define KSLICE (K_DIM / SPLIT)  // 2048
#define NITER (KSLICE / 32)     // 64 k-steps of 32

typedef __bf16 bf16x8 __attribute__((ext_vector_type(8)));
typedef float f32x4 __attribute__((ext_vector_type(4)));

// ---------------- W pack: fp32 [k][n] -> bf16 MFMA B-fragment order ----------------
// frag f = kb*16 + j   (kb = k/32, j = n/16); lane l = q*16 + la (q=(k>>3)&3, la=n&15),
// elem e = k&7:  Bp[f*512 + l*8 + e] = bf16(W[k][n]).
// A wave's fragment load is one 1KB lane-contiguous coalesced region, identical
// addresses across blocks of the same split -> stays resident in that XCD's L2.
__global__ __launch_bounds__(256) void wt_kernel(const float* __restrict__ W,
                                                 __bf16* __restrict__ Bp) {
  __shared__ float tile[32][257];
  const int kb = blockIdx.x;
  const int t = threadIdx.x;
#pragma unroll
  for (int r = 0; r < 8; ++r) {
    int idx4 = r * 256 + t;
    int kr = idx4 >> 6, c4 = idx4 & 63;
    f32x4 v = *(const f32x4*)(W + (size_t)(kb * 32 + kr) * N_DIM + c4 * 4);
#pragma unroll
    for (int u = 0; u < 4; ++u) tile[kr][c4 * 4 + u] = v[u];
  }
  __syncthreads();
#pragma unroll
  for (int rr = 0; rr < 4; ++rr) {
    int g = rr * 256 + t;
    int j = g >> 6, l = g & 63;
    int q = l >> 4, la = l & 15;
    bf16x8 o;
#pragma unroll
    for (int e = 0; e < 8; ++e) o[e] = (__bf16)tile[q * 8 + e][j * 16 + la];
    *(bf16x8*)(Bp + ((size_t)kb * 16 + j) * 512 + l * 8) = o;
  }
}

// ---------------- Main GEMM: barrier-free, LDS-free streaming MFMA ----------------
// 256 thr = 4 waves; wave w: rows m0+(w&1)*32..+32, cols (w>>1)*128..+128
// (2 m-tiles x 8 n-tiles = 16 MFMA/k-step, acc = 16 x f32x4 = 64 VGPR).
// A: fp32 global->reg, double-buffered (aE/aO), load-to-use = 2 k-steps.
// B: Bp fragments from L2, double-buffered (bE/bO), load-to-use = 2 k-steps.
// Zero barriers, zero LDS: 8 independent wave streams/CU, nothing can drain vmcnt.
// B traffic/XCD = 256 waves x 0.5 MB = 128 MB < L2 budget; A read 1x HBM + 1x L2.
// ysplit = bid&7 pins each K-split to one XCD (round-robin dispatch).
__global__ __launch_bounds__(256, 2) void gemm_kernel(const float* __restrict__ x,
                                                      const __bf16* __restrict__ Bp,
                                                      __bf16* __restrict__ part) {
  const int t = threadIdx.x;
  const int l = t & 63;
  const int w = t >> 6;
  const int rg = w & 1;   // row group: 32 rows
  const int nh = w >> 1;  // n-half: 128 cols
  const int la = l & 15, q = l >> 4;
  const int bid = blockIdx.x;
  const int ysplit = bid & 7;
  const int m0 = (bid >> 3) * 64;
  const int kbase = ysplit * KSLICE;

  const int r0 = m0 + rg * 32 + la;
  const float* ap0 = x + (size_t)r0 * K_DIM + kbase + q * 8;
  const float* ap1 = ap0 + (size_t)16 * K_DIM;

  // fragment base for this wave's 8 n-tiles; +jn*512 elem per frag, +8192/k-step
  const __bf16* bq = Bp + ((size_t)(kbase >> 5) * 16 + (size_t)nh * 8) * 512 + l * 8;

  f32x4 aE[4], aO[4];
  bf16x8 bE[8], bO[8];

  // ---- prologue: steps 0 (E) and 1 (O) ----
  aE[0] = *(const f32x4*)(ap0);      aE[1] = *(const f32x4*)(ap0 + 4);
  aE[2] = *(const f32x4*)(ap1);      aE[3] = *(const f32x4*)(ap1 + 4);
  aO[0] = *(const f32x4*)(ap0 + 32); aO[1] = *(const f32x4*)(ap0 + 36);
  aO[2] = *(const f32x4*)(ap1 + 32); aO[3] = *(const f32x4*)(ap1 + 36);
  ap0 += 64; ap1 += 64;  // -> step 2 base
#pragma unroll
  for (int jn = 0; jn < 8; ++jn) bE[jn] = *(const bf16x8*)(bq + jn * 512);
#pragma unroll
  for (int jn = 0; jn < 8; ++jn) bO[jn] = *(const bf16x8*)(bq + 8192 + jn * 512);
  bq += 16384;  // -> step 2 frags

  f32x4 acc[16];
  const f32x4 zero = {0.f, 0.f, 0.f, 0.f};
#pragma unroll
  for (int i = 0; i < 16; ++i) acc[i] = zero;

  // All register indices compile-time (rule #20): 2-step unroll with named E/O sets.
  // Refills for step KS+2 issue between the A-convert and the MFMAs of step KS.
#define STEP(KS, AR, BR, AOFF, BOFF)                                                 \
  {                                                                                  \
    bf16x8 af0, af1;                                                                 \
    _Pragma("unroll") for (int e = 0; e < 4; ++e) {                                  \
      af0[e] = (__bf16)AR[0][e]; af0[e + 4] = (__bf16)AR[1][e];                      \
      af1[e] = (__bf16)AR[2][e]; af1[e + 4] = (__bf16)AR[3][e];                      \
    }                                                                                \
    if ((KS) + 2 < NITER) { /* refill this A set for step KS+2 */                    \
      AR[0] = *(const f32x4*)(ap0 + (AOFF));      AR[1] = *(const f32x4*)(ap0 + (AOFF) + 4); \
      AR[2] = *(const f32x4*)(ap1 + (AOFF));      AR[3] = *(const f32x4*)(ap1 + (AOFF) + 4); \
    }                                                                                \
    _Pragma("unroll") for (int jn = 0; jn < 8; ++jn) {                               \
      acc[jn] = __builtin_amdgcn_mfma_f32_16x16x32_bf16(af0, BR[jn], acc[jn], 0, 0, 0); \
      acc[8 + jn] =                                                                  \
          __builtin_amdgcn_mfma_f32_16x16x32_bf16(af1, BR[jn], acc[8 + jn], 0, 0, 0); \
      if ((KS) + 2 < NITER) /* reload this B set for step KS+2, right after use */   \
        BR[jn] = *(const bf16x8*)(bq + (BOFF) + jn * 512);                           \
    }                                                                                \
  }

  for (int ks = 0; ks < NITER; ks += 2) {
    STEP(ks, aE, bE, 0, 0)
    STEP(ks + 1, aO, bO, 32, 8192)
    ap0 += 64; ap1 += 64; bq += 16384;
  }
#undef STEP

  // ---- epilogue: bf16 partials (C/D layout: col=lane&15, row=quad*4+reg) ----
  __bf16* pbase = part + (size_t)ysplit * ((size_t)M_DIM * N_DIM);
  const int orow = m0 + rg * 32 + q * 4;
  const int ocol = nh * 128 + la;
#pragma unroll
  for (int mt = 0; mt < 2; ++mt)
#pragma unroll
    for (int jn = 0; jn < 8; ++jn)
#pragma unroll
      for (int r = 0; r < 4; ++r)
        pbase[(size_t)(orow + mt * 16 + r) * N_DIM + ocol + jn * 16] =
            (__bf16)acc[mt * 8 + jn][r];
}

// ---------------- reduce partials + exact fp32 bit-flip correction + bias ----------------
__global__ __launch_bounds__(256) void reduce_kernel(const __bf16* __restrict__ part,
                                                     const float* __restrict__ x,
                                                     const float* __restrict__ W,
                                                     const float* __restrict__ bvec,
                                                     const float* __restrict__ coeffp,
                                                     const int* __restrict__ idx,
                                                     const int* __restrict__ bp,
                                                     float* __restrict__ out) {
  const int row = blockIdx.x;
  const int o = threadIdx.x;
  const int iv = idx[row];
  const float g = x[(size_t)row * K_DIM + iv];
  const int bits = __float_as_int(g) ^ (1 << bp[row]);
  const float upd = __int_as_float(bits) - g;  // swap_sim(g) - g, exact fp32
  const float coeff = coeffp[0];
  const size_t off = (size_t)row * N_DIM + o;
  float sum = 0.f;
#pragma unroll
  for (int s = 0; s < SPLIT; ++s)
    sum += (float)part[(size_t)s * ((size_t)M_DIM * N_DIM) + off];
  out[off] = sum + coeff * upd * W[(size_t)iv * N_DIM + o] + bvec[o];
}

extern "C" void kernel_launch(void* const* d_in, const int* in_sizes, int n_in,
                              void* d_out, int out_size, void* d_ws, size_t ws_size,
                              hipStream_t stream) {
  const float* x = (const float*)d_in[0];
  const float* W = (const float*)d_in[1];
  const float* b = (const float*)d_in[2];
  const float* coeff = (const float*)d_in[3];
  const int* idx = (const int*)d_in[4];
  const int* bp = (const int*)d_in[5];
  float* out = (float*)d_out;

  __bf16* Bp = (__bf16*)d_ws;
  const size_t bp_bytes = (size_t)K_DIM * N_DIM * 2;  // 8 MiB
  __bf16* part = (__bf16*)((char*)d_ws + bp_bytes);   // SPLIT x 2 MiB bf16 partials

  hipLaunchKernelGGL(wt_kernel, dim3(K_DIM / 32), dim3(256), 0, stream, W, Bp);
  hipLaunchKernelGGL(gemm_kernel, dim3((M_DIM / 64) * SPLIT), dim3(256), 0, stream,
                     x, Bp, part);
  hipLaunchKernelGGL(reduce_kernel, dim3(M_DIM), dim3(256), 0, stream,
                     part, x, W, b, coeff, idx, bp, out);
}

// Round 5
// 404.243 us; speedup vs baseline: 1.0628x; 1.0628x over previous
//
#include <hip/hip_runtime.h>

#define M_DIM 4096
#define K_DIM 16384
#define N_DIM 256
#define SPLIT 8
#define BK 64
#define KSLICE (K_DIM / SPLIT)
#define NITER (KSLICE / BK)  // 32

typedef __bf16 bf16x8 __attribute__((ext_vector_type(8)));
typedef __bf16 bf16x4 __attribute__((ext_vector_type(4)));
typedef float f32x4 __attribute__((ext_vector_type(4)));

// ---------------- W transpose + convert: Wt[n][k] = bf16(W[k][n]) ----------------
__global__ __launch_bounds__(256) void wt_kernel(const float* __restrict__ W,
                                                 __bf16* __restrict__ Wt) {
  __shared__ float tile[64][65];
  const int k0 = blockIdx.x * 64, n0 = blockIdx.y * 64;
  const int t = threadIdx.x;
#pragma unroll
  for (int r = 0; r < 4; ++r) {
    int idx4 = r * 256 + t;
    int kr = idx4 >> 4, c4 = idx4 & 15;
    f32x4 v = *(const f32x4*)(W + (size_t)(k0 + kr) * N_DIM + n0 + c4 * 4);
#pragma unroll
    for (int j = 0; j < 4; ++j) tile[kr][c4 * 4 + j] = v[j];
  }
  __syncthreads();
#pragma unroll
  for (int r = 0; r < 4; ++r) {
    int nr = (t >> 4) + r * 16, k4 = t & 15;
    bf16x4 o;
#pragma unroll
    for (int j = 0; j < 4; ++j) o[j] = (__bf16)tile[k4 * 4 + j][nr];
    *(bf16x4*)(Wt + (size_t)(n0 + nr) * K_DIM + k0 + k4 * 4) = o;
  }
}

// ---------------- Main MFMA GEMM: round-0 structure + XCD-pinned K-splits ----------
// BM=64, BN=256, BK=64, 256 thr = 4 waves; wave w owns 64m x 64n at n=w*64
// (4x4 tiles of mfma_f32_16x16x32_bf16). Loads for iter k+1 are issued after the
// LDS-ready barrier of iter k and complete under the MFMA phase.
// LDS = As 64x72 (9 KiB) + Bs 256x72 (36 KiB) = 45 KiB -> 3 blocks/CU capacity.
// XCD pinning (T1): 1-D grid of 512, split = bid&7. Round-robin dispatch puts
// split s on XCD s, so each XCD's B working set is its private 1 MiB Wt slice
// (L2-resident, reused 64x) instead of thrashing 8 MiB through a 4 MiB L2.
// 512 % 8 == 0 -> bijective mapping. Co-resident pairs (bid, bid+256) share a split.
__global__ __launch_bounds__(256, 3) void gemm_kernel(const float* __restrict__ x,
                                                      const __bf16* __restrict__ Wt,
                                                      __bf16* __restrict__ part) {
  __shared__ __bf16 As[64 * 72];
  __shared__ __bf16 Bs[256 * 72];

  const int t = threadIdx.x;
  const int l = t & 63;
  const int w = t >> 6;
  const int la = l & 15, q = l >> 4;
  const int bid = blockIdx.x;
  const int ysplit = bid & 7;           // -> XCD ysplit (round-robin dispatch)
  const int m0 = (bid >> 3) * 64;
  const int kbase = ysplit * KSLICE;

  // A staging: 4 float4/thread covering 64 rows x 64 k
  const int arow = t >> 4, ac4 = t & 15;
  // B staging: 8 x 16B/thread covering 256 rows x 64 k (8 lanes per 128B row seg)
  const int bn = t >> 3, bk8 = (t & 7) * 8;

  const float* ap = x + (size_t)(m0 + arow) * K_DIM + kbase + ac4 * 4;
  const __bf16* bp = Wt + (size_t)bn * K_DIM + kbase + bk8;

  f32x4 areg[4];
  bf16x8 breg[8];

  // prologue: prefetch iter 0
#pragma unroll
  for (int r = 0; r < 4; ++r) areg[r] = *(const f32x4*)(ap + (size_t)r * 16 * K_DIM);
#pragma unroll
  for (int c = 0; c < 8; ++c) breg[c] = *(const bf16x8*)(bp + (size_t)c * 32 * K_DIM);

  f32x4 acc[4][4];
  const f32x4 zero = {0.f, 0.f, 0.f, 0.f};
#pragma unroll
  for (int i = 0; i < 4; ++i)
#pragma unroll
    for (int j = 0; j < 4; ++j) acc[i][j] = zero;

  for (int it = 0; it < NITER; ++it) {
    __syncthreads();  // previous MFMA phase done reading LDS
    // ---- commit prefetched regs to LDS (compiler waits vmcnt here, per-wave) ----
#pragma unroll
    for (int r = 0; r < 4; ++r) {
      bf16x4 o = {(__bf16)areg[r][0], (__bf16)areg[r][1],
                  (__bf16)areg[r][2], (__bf16)areg[r][3]};
      *(bf16x4*)(&As[(arow + r * 16) * 72 + ac4 * 4]) = o;
    }
#pragma unroll
    for (int c = 0; c < 8; ++c)
      *(bf16x8*)(&Bs[(bn + c * 32) * 72 + bk8]) = breg[c];
    __syncthreads();  // LDS ready

    // ---- issue next iteration's global loads; they fly under the MFMAs ----
    if (it + 1 < NITER) {
      ap += BK;
      bp += BK;
#pragma unroll
      for (int r = 0; r < 4; ++r) areg[r] = *(const f32x4*)(ap + (size_t)r * 16 * K_DIM);
#pragma unroll
      for (int c = 0; c < 8; ++c) breg[c] = *(const bf16x8*)(bp + (size_t)c * 32 * K_DIM);
    }

    // ---- 32 MFMAs per wave ----
#pragma unroll
    for (int ks = 0; ks < 2; ++ks) {
      const int kb = ks * 32 + q * 8;
      bf16x8 a[4], b[4];
#pragma unroll
      for (int i = 0; i < 4; ++i)
        a[i] = *(const bf16x8*)(&As[(i * 16 + la) * 72 + kb]);
#pragma unroll
      for (int j = 0; j < 4; ++j)
        b[j] = *(const bf16x8*)(&Bs[(w * 64 + j * 16 + la) * 72 + kb]);
#pragma unroll
      for (int i = 0; i < 4; ++i)
#pragma unroll
        for (int j = 0; j < 4; ++j)
          acc[i][j] = __builtin_amdgcn_mfma_f32_16x16x32_bf16(a[i], b[j], acc[i][j], 0, 0, 0);
    }
  }

  // ---- epilogue: bf16 partials (C/D layout: col=lane&15, row=quad*4+reg) ----
  __bf16* pbase = part + (size_t)ysplit * ((size_t)M_DIM * N_DIM);
#pragma unroll
  for (int i = 0; i < 4; ++i) {
    int r0 = m0 + i * 16 + q * 4;
#pragma unroll
    for (int j = 0; j < 4; ++j) {
      int c = w * 64 + j * 16 + la;
#pragma unroll
      for (int r = 0; r < 4; ++r)
        pbase[(size_t)(r0 + r) * N_DIM + c] = (__bf16)acc[i][j][r];
    }
  }
}

// ---------------- reduce partials + exact fp32 bit-flip correction + bias ----------------
__global__ __launch_bounds__(256) void reduce_kernel(const __bf16* __restrict__ part,
                                                     const float* __restrict__ x,
                                                     const float* __restrict__ W,
                                                     const float* __restrict__ bvec,
                                                     const float* __restrict__ coeffp,
                                                     const int* __restrict__ idx,
                                                     const int* __restrict__ bp,
                                                     float* __restrict__ out) {
  const int row = blockIdx.x;
  const int o = threadIdx.x;
  const int iv = idx[row];
  const float g = x[(size_t)row * K_DIM + iv];
  const int bits = __float_as_int(g) ^ (1 << bp[row]);
  const float upd = __int_as_float(bits) - g;  // swap_sim(g) - g, exact fp32
  const float coeff = coeffp[0];
  const size_t off = (size_t)row * N_DIM + o;
  float sum = 0.f;
#pragma unroll
  for (int s = 0; s < SPLIT; ++s)
    sum += (float)part[(size_t)s * ((size_t)M_DIM * N_DIM) + off];
  out[off] = sum + coeff * upd * W[(size_t)iv * N_DIM + o] + bvec[o];
}

extern "C" void kernel_launch(void* const* d_in, const int* in_sizes, int n_in,
                              void* d_out, int out_size, void* d_ws, size_t ws_size,
                              hipStream_t stream) {
  const float* x = (const float*)d_in[0];
  const float* W = (const float*)d_in[1];
  const float* b = (const float*)d_in[2];
  const float* coeff = (const float*)d_in[3];
  const int* idx = (const int*)d_in[4];
  const int* bp = (const int*)d_in[5];
  float* out = (float*)d_out;

  __bf16* Wt = (__bf16*)d_ws;
  const size_t wt_bytes = (size_t)K_DIM * N_DIM * 2;  // 8 MiB
  __bf16* part = (__bf16*)((char*)d_ws + wt_bytes);   // 8 x 2 MiB bf16 partials

  hipLaunchKernelGGL(wt_kernel, dim3(K_DIM / 64, N_DIM / 64), dim3(256), 0, stream, W, Wt);
  hipLaunchKernelGGL(gemm_kernel, dim3((M_DIM / 64) * SPLIT), dim3(256), 0, stream,
                     x, Wt, part);
  hipLaunchKernelGGL(reduce_kernel, dim3(M_DIM), dim3(256), 0, stream,
                     part, x, W, b, coeff, idx, bp, out);
}